// Round 20
// baseline (39.975 us; speedup 1.0000x reference)
//
#include <hip/hip_runtime.h>
#include <cstddef>

// Hyperbolic supervised contrastive loss, fused, MFMA bf16 Gram, symmetric.
// G ~= bf16(F) bf16(F)^T (validated r12-r19, absmax 0.0 vs threshold 9.4e-2).
// logits_max cancels (softmax shift invariance).
// EPILOGUE IDENTITY (r19-proven): num_sq = (si + sj - 2g) * den,
//   den = 1 - 2Cg + C^2*si*sj >= 0.
// r20: 64x128 tiles, wedge bi <= 2bj+1 (nbj=32 -> 1056 blocks ~= ONE resident
// round at 4 blocks/CU) -- r19 ran 2080 blocks = 1.6 rounds + 2x fixed costs.
// Unique-writer partials with per-half row accumulators:
//   cell (s, rb):  s > rb  <- row-half s of tile (rb, s/2)
//                  s < rb  <- col-half of tile (s, rb/2)
//                  s == rb <- combined at tile (rb, rb/2)
// (halves with h < bi are fully masked-zero and skipped; verified 1 writer/cell)
// NO atomics, no zero-init. launch_bounds(256,4) = 128-VGPR cap (spill-free
// r17-r19; r16's (256,8)=64-cap caused 143 MB scratch disaster).
// B-tile 32 KB LDS, 16B-chunk XOR swizzle (c ^= row&7), pre-swizzled source.
// exp(logit) = ratio^20 via 5 mults; logit = 20*ln2*log2(ratio).

typedef __bf16 bf16x8 __attribute__((ext_vector_type(8)));
typedef __bf16 bf16x4 __attribute__((ext_vector_type(4)));
typedef float  f32x4  __attribute__((ext_vector_type(4)));

#define C_CONST 0.01f
#define RATIO_MIN 5.000025e-06f           // ratio at clamp 1-1e-5
#define LOGIT_SCALE 13.86294361119890619f // 20*ln(2)
#define TEMP 0.5f
#define LN2 0.69314718055994530942f
constexpr int DD = 128;
constexpr int NSPLIT = 64;
constexpr int FBLK = 16;

// bf16 convert + row squared-norms + zero done-counter. 8 rows/block.
__global__ __launch_bounds__(256) void prep_kernel(
    const float* __restrict__ F, __bf16* __restrict__ Fh, float* __restrict__ sq,
    unsigned int* __restrict__ cnt) {
  const int tid = threadIdx.x;
  const int lane = tid & 31;
  const int row = blockIdx.x * 8 + (tid >> 5);
  if (blockIdx.x == 0 && tid == 0) *cnt = 0u;
  const float4 v = *reinterpret_cast<const float4*>(F + (size_t)row * DD + lane * 4);
  float s = v.x * v.x + v.y * v.y + v.z * v.z + v.w * v.w;
  bf16x4 h;
  h[0] = (__bf16)v.x; h[1] = (__bf16)v.y; h[2] = (__bf16)v.z; h[3] = (__bf16)v.w;
  *reinterpret_cast<bf16x4*>(Fh + (size_t)row * DD + lane * 4) = h;
#pragma unroll
  for (int off = 1; off < 32; off <<= 1) s += __shfl_xor(s, off);
  if (lane == 0) sq[row] = s;
}

// 64-row x 128-col tile; 4 waves, wave w owns rows row0..row0+15.
// C/D layout (verified m89): value r of frag fj at
// row = row0 + lg*4 + r, col = col0 + fj*16 + ln.
__global__ __launch_bounds__(256, 4) void gram_kernel(
    const __bf16* __restrict__ Fh,
    const float* __restrict__ sq, const int* __restrict__ labels,
    float* __restrict__ dpart, float* __restrict__ ppart, float* __restrict__ npart,
    int B) {
  __shared__ __bf16 Bs[128 * 128];          // 32 KB B-tile, chunk-XOR swizzle
  __shared__ float colAcc[4][3][128];       // per-wave col-side slices (6 KB)
  __shared__ float rowAcc[4][6][16];        // per-wave row halves L/H (1.5 KB)
  char* BsB = reinterpret_cast<char*>(Bs);

  const int tid = threadIdx.x;
  const int l  = tid & 63;
  const int w  = tid >> 6;
  const int lg = l >> 4, ln = l & 15;
  const int lx = ln & 7;

  // wedge decode: t -> (bi, bj), bi in [0, min(64, 2bj+2)). S(bj) = bj^2 + bj.
  const int t = blockIdx.x;
  int bj = (int)((sqrtf((float)(4 * t + 1)) - 1.f) * 0.5f);
  while (bj * bj + bj > t) --bj;
  while ((bj + 1) * (bj + 1) + (bj + 1) <= t) ++bj;
  const int bi = t - (bj * bj + bj);

  const int row0 = bi * 64 + w * 16;
  const int col0 = bj * 128;

  // --- stage B tile (128 rows x 128 dims): linear dest, pre-swizzled source
  // LDS chunk k (16B) of row r holds global chunk ((k&15) ^ (r&7)) of row r.
#pragma unroll
  for (int j = 0; j < 8; ++j) {
    const int k = tid + j * 256;            // chunk id 0..2047
    const int row = k >> 4;
    const int cc = (k & 15) ^ (row & 7);
    bf16x8 v = *reinterpret_cast<const bf16x8*>(Fh + (size_t)(col0 + row) * DD + cc * 8);
    *reinterpret_cast<bf16x8*>(BsB + (size_t)k * 16) = v;
  }

  // --- A fragments to regs (16 VGPR)
  const __bf16* Ahp = Fh + (size_t)(row0 + ln) * DD + lg * 8;
  bf16x8 ah[4];
#pragma unroll
  for (int kt = 0; kt < 4; ++kt)
    ah[kt] = *reinterpret_cast<const bf16x8*>(Ahp + kt * 32);

  // --- row/col metadata hoisted pre-barrier
  float si[4], c2si[4]; int li[4];
#pragma unroll
  for (int r = 0; r < 4; ++r) {
    const int row = row0 + lg * 4 + r;
    si[r] = sq[row];
    c2si[r] = (C_CONST * C_CONST) * si[r];
    li[r] = labels[row];
  }
  float sqj[8]; int labj[8];
#pragma unroll
  for (int fj = 0; fj < 8; ++fj) {
    sqj[fj]  = sq[col0 + fj * 16 + ln];
    labj[fj] = labels[col0 + fj * 16 + ln];
  }

  __syncthreads();

  float dacc[2][4] = {}, pacc[2][4] = {}, nacc[2][4] = {};  // [half][r]

#pragma unroll
  for (int fj = 0; fj < 8; ++fj) {
    const int hh = fj >> 2;                 // 0: cols 0-63 (split 2bj), 1: 64-127
    // 4 ds_read_b128 (swizzled)
    const int rbase = (fj * 16 + ln) * 256;
    bf16x8 bh[4];
#pragma unroll
    for (int kt = 0; kt < 4; ++kt)
      bh[kt] = *reinterpret_cast<const bf16x8*>(BsB + rbase + ((((kt * 4 + lg) ^ lx)) << 4));

    f32x4 acc = (f32x4){0.f, 0.f, 0.f, 0.f};
#pragma unroll
    for (int kt = 0; kt < 4; ++kt)
      acc = __builtin_amdgcn_mfma_f32_16x16x32_bf16(ah[kt], bh[kt], acc, 0, 0, 0);

    // fused epilogue (identity-simplified)
    const int col = col0 + fj * 16 + ln;
    const float sjv = sqj[fj];
    const int   ljv = labj[fj];
    float cd = 0.f, cp = 0.f, cn = 0.f;
#pragma unroll
    for (int r = 0; r < 4; ++r) {
      const int row = row0 + lg * 4 + r;
      const float g   = acc[r];
      const float tt  = fmaf(-2.f * C_CONST, g, 1.f);   // 1 - 2Cg
      const float den = fmaf(c2si[r], sjv, tt);         // 1-2Cg+C^2 si sj (>=0)
      const float dd  = fmaf(-2.f, g, si[r] + sjv);     // |xi-xj|^2
      const float ns  = fmaxf(dd * den, 0.f);
      const float rr  = __builtin_amdgcn_sqrtf(C_CONST * ns);
      const float dA  = fabsf(den);
      float ratio = (dA - rr) * __builtin_amdgcn_rcpf(dA + rr);
      ratio = fmaxf(ratio, RATIO_MIN);
      const float P = __builtin_amdgcn_logf(ratio);     // log2(ratio)
      const float t2 = ratio * ratio;                   // e = ratio^20
      const float t4 = t2 * t2;
      const float t5 = t4 * ratio;
      const float t10 = t5 * t5;
      const float e = t10 * t10;
      const bool mask = row < col;                      // strict upper: once/pair
      const bool same = mask && (ljv == li[r]);
      const float ev = mask ? e : 0.f;
      const float pv = same ? LOGIT_SCALE * P : 0.f;
      const float nv = same ? 1.f : 0.f;
      dacc[hh][r] += ev; pacc[hh][r] += pv; nacc[hh][r] += nv;
      cd += ev; cp += pv; cn += nv;
    }
    // col-side: reduce over the 4 lg groups; per-wave LDS slice
    cd += __shfl_xor(cd, 16); cd += __shfl_xor(cd, 32);
    cp += __shfl_xor(cp, 16); cp += __shfl_xor(cp, 32);
    cn += __shfl_xor(cn, 16); cn += __shfl_xor(cn, 32);
    if (l < 16) {
      colAcc[w][0][fj * 16 + ln] = cd;
      colAcc[w][1][fj * 16 + ln] = cp;
      colAcc[w][2][fj * 16 + ln] = cn;
    }
  }

  // row-side: reduce over the 16 ln lanes -> per-wave LDS slices (L and H)
#pragma unroll
  for (int hh = 0; hh < 2; ++hh)
#pragma unroll
    for (int r = 0; r < 4; ++r) {
      float d = dacc[hh][r], p = pacc[hh][r], n = nacc[hh][r];
#pragma unroll
      for (int off = 1; off < 16; off <<= 1) {
        d += __shfl_xor(d, off);
        p += __shfl_xor(p, off);
        n += __shfl_xor(n, off);
      }
      if (ln == 0) {
        rowAcc[w][hh * 3 + 0][lg * 4 + r] = d;
        rowAcc[w][hh * 3 + 1][lg * 4 + r] = p;
        rowAcc[w][hh * 3 + 2][lg * 4 + r] = n;
      }
    }

  __syncthreads();

  // col sums reduced in place (colAcc[0] row holds the total afterwards)
  if (tid < 128) {
#pragma unroll
    for (int s3 = 0; s3 < 3; ++s3)
      colAcc[0][s3][tid] = colAcc[0][s3][tid] + colAcc[1][s3][tid]
                         + colAcc[2][s3][tid] + colAcc[3][s3][tid];
  }
  __syncthreads();

  // unique-writer coalesced partial stores (no atomics, no init):
  //   row-half h -> cell (h, bi) when h > bi; combined (+col-half) when h == bi
  //   col-half h -> cell (bi, h) when h > bi
  const int hL = 2 * bj, hH = 2 * bj + 1;
  if (tid < 64) {
    const int ww = tid >> 4, ii = tid & 15;
    const float rL0 = rowAcc[ww][0][ii], rL1 = rowAcc[ww][1][ii], rL2 = rowAcc[ww][2][ii];
    const float rH0 = rowAcc[ww][3][ii], rH1 = rowAcc[ww][4][ii], rH2 = rowAcc[ww][5][ii];
    if (bi == hL) {            // combined L at (bi,bi); plain H
      const size_t ci = (size_t)hL * B + bi * 64 + tid;
      dpart[ci] = rL0 + colAcc[0][0][tid];
      ppart[ci] = rL1 + colAcc[0][1][tid];
      npart[ci] = rL2 + colAcc[0][2][tid];
      const size_t hi = (size_t)hH * B + bi * 64 + tid;
      dpart[hi] = rH0; ppart[hi] = rH1; npart[hi] = rH2;
    } else if (bi == hH) {     // combined H at (bi,bi); L half fully masked-zero
      const size_t ci = (size_t)hH * B + bi * 64 + tid;
      dpart[ci] = rH0 + colAcc[0][0][64 + tid];
      ppart[ci] = rH1 + colAcc[0][1][64 + tid];
      npart[ci] = rH2 + colAcc[0][2][64 + tid];
    } else {                   // bi < hL: both plain
      const size_t li_ = (size_t)hL * B + bi * 64 + tid;
      dpart[li_] = rL0; ppart[li_] = rL1; npart[li_] = rL2;
      const size_t hi = (size_t)hH * B + bi * 64 + tid;
      dpart[hi] = rH0; ppart[hi] = rH1; npart[hi] = rH2;
    }
  }
  if (tid < 128) {
    const int h = 2 * bj + (tid >> 6);
    if (h > bi) {
      const size_t ci = (size_t)bi * B + h * 64 + (tid & 63);
      dpart[ci] = colAcc[0][0][tid];
      ppart[ci] = colAcc[0][1][tid];
      npart[ci] = colAcc[0][2][tid];
    }
  }
}

// single finalize kernel: 16 blocks; per-block partial, last block reduces.
__global__ __launch_bounds__(256) void finalize_kernel(
    const float* __restrict__ dpart, const float* __restrict__ ppart,
    const float* __restrict__ npart, float* __restrict__ lossP,
    float* __restrict__ validP, unsigned int* __restrict__ cnt,
    float* __restrict__ out, int B) {
  const int tid = threadIdx.x;
  const int i = blockIdx.x * 256 + tid;
  float d = 0.f, p = 0.f, n = 0.f;
#pragma unroll 8
  for (int s = 0; s < NSPLIT; ++s) {
    d += dpart[(size_t)s * B + i];     // coalesced across threads
    p += ppart[(size_t)s * B + i];
    n += npart[(size_t)s * B + i];
  }
  float s_loss = 0.f, s_valid = 0.f;
  if (n > 0.f) {
    float ln_d = __builtin_amdgcn_logf(d) * LN2;
    float rl = -(p - n * ln_d) / n * TEMP;
    if (!(rl != rl)) s_loss = rl;      // NaN -> 0 like reference
    s_valid = 1.f;
  }
#pragma unroll
  for (int off = 1; off < 64; off <<= 1) {
    s_loss += __shfl_xor(s_loss, off);
    s_valid += __shfl_xor(s_valid, off);
  }
  __shared__ float red[8];
  const int wid = tid >> 6;
  if ((tid & 63) == 0) { red[wid] = s_loss; red[wid + 4] = s_valid; }
  __syncthreads();
  if (tid == 0) {
    lossP[blockIdx.x]  = red[0] + red[1] + red[2] + red[3];
    validP[blockIdx.x] = red[4] + red[5] + red[6] + red[7];
  }

  // last-block final reduce (16 threadfences total -- negligible)
  __threadfence();
  __shared__ unsigned int lastFlag;
  if (tid == 0)
    lastFlag = (atomicAdd(cnt, 1u) == (unsigned)(FBLK - 1)) ? 1u : 0u;
  __syncthreads();
  if (lastFlag != 0u && tid < 64) {
    float L = 0.f, V = 0.f;
    if (tid < FBLK) {
      L = __hip_atomic_load(&lossP[tid],  __ATOMIC_RELAXED, __HIP_MEMORY_SCOPE_AGENT);
      V = __hip_atomic_load(&validP[tid], __ATOMIC_RELAXED, __HIP_MEMORY_SCOPE_AGENT);
    }
#pragma unroll
    for (int off = 1; off < 64; off <<= 1) {
      L += __shfl_xor(L, off);
      V += __shfl_xor(V, off);
    }
    if (tid == 0) out[0] = L / fmaxf(V, 1.f);
  }
}

extern "C" void kernel_launch(void* const* d_in, const int* in_sizes, int n_in,
                              void* d_out, int out_size, void* d_ws, size_t ws_size,
                              hipStream_t stream) {
  const float* F = (const float*)d_in[0];
  const int* labels = (const int*)d_in[1];
  const int B = in_sizes[1];           // 4096

  float* sq    = (float*)d_ws;
  float* dpart = sq + B;
  float* ppart = dpart + (size_t)NSPLIT * B;
  float* npart = ppart + (size_t)NSPLIT * B;
  float* lossP = npart + (size_t)NSPLIT * B;
  float* validP = lossP + FBLK;
  unsigned int* cnt = (unsigned int*)(validP + FBLK);
  __bf16* Fh = (__bf16*)(cnt + 64);    // 256B-aligned pad

  const int nbj = B / 128;               // 32
  const int nblocks = nbj * nbj + nbj;   // 1056

  prep_kernel<<<dim3(B / 8), dim3(256), 0, stream>>>(F, Fh, sq, cnt);
  gram_kernel<<<dim3(nblocks), dim3(256), 0, stream>>>(
      Fh, sq, labels, dpart, ppart, npart, B);
  finalize_kernel<<<dim3(FBLK), dim3(256), 0, stream>>>(
      dpart, ppart, npart, lossP, validP, cnt, (float*)d_out, B);
}

// Round 21
// 34.083 us; speedup vs baseline: 1.1729x; 1.1729x over previous
//
#include <hip/hip_runtime.h>
#include <cstddef>

// Hyperbolic supervised contrastive loss, fused, MFMA bf16 Gram, symmetric.
// G ~= bf16(F) bf16(F)^T (validated r12-r20, absmax 0.0 vs threshold 9.4e-2).
// logits_max cancels (softmax shift invariance).
// == r19 configuration (measured best: 34.0us; r20's 64x128 consolidation
// regressed to 40.0 -- block-count consolidation is NOT a lever here) ==
// EPILOGUE IDENTITY (r19-proven): num_sq = (si + sj - 2g) * den,
//   den = 1 - 2Cg + C^2*si*sj >= 0.
// launch_bounds(256,4) = 128-VGPR cap: spill-free (r16's (256,8)=64-cap
// caused 143 MB scratch traffic -- the dominant failure mode found).
// NO GLOBAL ATOMICS: wedge gives every (split,row) partial a unique writer:
//   entry (s, r), br=r/64:  br<s -> block (br,s) row-side
//                           br>s -> block (s,br) col-side
//                           br==s -> diagonal block stores row+col sum
// 64x64 tiles, triangular wedge bi<=bj (nt=64, 2080 blocks), LDS ~20 KB.
// B-tile 16B-chunk XOR swizzle (c ^= row&7), linear dest + pre-swizzled src.
// Finalize: ONE kernel (16 blocks + done-counter; last block reduces).
// exp(logit) = ratio^20 via 5 mults; logit = 20*ln2*log2(ratio).

typedef __bf16 bf16x8 __attribute__((ext_vector_type(8)));
typedef __bf16 bf16x4 __attribute__((ext_vector_type(4)));
typedef float  f32x4  __attribute__((ext_vector_type(4)));

#define C_CONST 0.01f
#define RATIO_MIN 5.000025e-06f           // ratio at clamp 1-1e-5
#define LOGIT_SCALE 13.86294361119890619f // 20*ln(2)
#define TEMP 0.5f
#define LN2 0.69314718055994530942f
constexpr int DD = 128;
constexpr int NSPLIT = 64;                // = nt
constexpr int FBLK = 16;

// bf16 convert + row squared-norms + zero done-counter. 8 rows/block.
__global__ __launch_bounds__(256) void prep_kernel(
    const float* __restrict__ F, __bf16* __restrict__ Fh, float* __restrict__ sq,
    unsigned int* __restrict__ cnt) {
  const int tid = threadIdx.x;
  const int lane = tid & 31;
  const int row = blockIdx.x * 8 + (tid >> 5);
  if (blockIdx.x == 0 && tid == 0) *cnt = 0u;
  const float4 v = *reinterpret_cast<const float4*>(F + (size_t)row * DD + lane * 4);
  float s = v.x * v.x + v.y * v.y + v.z * v.z + v.w * v.w;
  bf16x4 h;
  h[0] = (__bf16)v.x; h[1] = (__bf16)v.y; h[2] = (__bf16)v.z; h[3] = (__bf16)v.w;
  *reinterpret_cast<bf16x4*>(Fh + (size_t)row * DD + lane * 4) = h;
#pragma unroll
  for (int off = 1; off < 32; off <<= 1) s += __shfl_xor(s, off);
  if (lane == 0) sq[row] = s;
}

// 64x64 tile; 4 waves, wave w owns rows row0..row0+15 (1 row-frag x 4 col-frags).
// C/D layout (verified m89): value r of frag fj at
// row = row0 + lg*4 + r, col = col0 + fj*16 + ln.
__global__ __launch_bounds__(256, 4) void gram_kernel(
    const __bf16* __restrict__ Fh,
    const float* __restrict__ sq, const int* __restrict__ labels,
    float* __restrict__ dpart, float* __restrict__ ppart, float* __restrict__ npart,
    int B, int nt) {
  __shared__ __bf16 Bs[64 * 128];           // 16 KB B-tile, chunk-XOR swizzle
  __shared__ float colAcc[4][3][64];        // per-wave col-side slices (3 KB)
  __shared__ float rowAcc[4][3][16];        // per-wave row-side slices (768 B)
  char* BsB = reinterpret_cast<char*>(Bs);

  const int tid = threadIdx.x;
  const int l  = tid & 63;
  const int w  = tid >> 6;
  const int lg = l >> 4, ln = l & 15;
  const int lx = ln & 7;

  // triangular decode: block t -> (bi, bj), bi <= bj. S(bi) = bi*nt - bi(bi-1)/2
  const int t = blockIdx.x;
  int bi = (int)((2 * nt + 1 - sqrtf((float)((2 * nt + 1) * (2 * nt + 1) - 8 * t))) * 0.5f);
  while ((bi + 1) * nt - ((bi + 1) * bi) / 2 <= t) ++bi;
  while (bi * nt - (bi * (bi - 1)) / 2 > t) --bi;
  const int bj = bi + (t - (bi * nt - (bi * (bi - 1)) / 2));

  const int row0 = bi * 64 + w * 16;
  const int col0 = bj * 64;

  // --- stage B tile (64 rows x 128 dims) into LDS: linear dest, pre-swizzled src
  // LDS chunk k (16B) of row r holds global chunk ((k&15) ^ (r&7)) of row r.
#pragma unroll
  for (int j = 0; j < 4; ++j) {
    const int k = tid + j * 256;            // chunk id 0..1023
    const int row = k >> 4;
    const int cc = (k & 15) ^ (row & 7);
    bf16x8 v = *reinterpret_cast<const bf16x8*>(Fh + (size_t)(col0 + row) * DD + cc * 8);
    *reinterpret_cast<bf16x8*>(BsB + (size_t)k * 16) = v;
  }

  // --- A fragments to regs (16 VGPR)
  const __bf16* Ahp = Fh + (size_t)(row0 + ln) * DD + lg * 8;
  bf16x8 ah[4];
#pragma unroll
  for (int kt = 0; kt < 4; ++kt)
    ah[kt] = *reinterpret_cast<const bf16x8*>(Ahp + kt * 32);

  // --- row/col metadata hoisted pre-barrier
  float si[4], c2si[4]; int li[4];
#pragma unroll
  for (int r = 0; r < 4; ++r) {
    const int row = row0 + lg * 4 + r;
    si[r] = sq[row];
    c2si[r] = (C_CONST * C_CONST) * si[r];
    li[r] = labels[row];
  }
  float sqj[4]; int labj[4];
#pragma unroll
  for (int fj = 0; fj < 4; ++fj) {
    sqj[fj]  = sq[col0 + fj * 16 + ln];
    labj[fj] = labels[col0 + fj * 16 + ln];
  }

  __syncthreads();

  float dacc[4] = {}, pacc[4] = {}, nacc[4] = {};

#pragma unroll
  for (int fj = 0; fj < 4; ++fj) {
    // 4 ds_read_b128 (swizzled)
    const int rbase = (fj * 16 + ln) * 256;
    bf16x8 bh[4];
#pragma unroll
    for (int kt = 0; kt < 4; ++kt)
      bh[kt] = *reinterpret_cast<const bf16x8*>(BsB + rbase + ((((kt * 4 + lg) ^ lx)) << 4));

    f32x4 acc = (f32x4){0.f, 0.f, 0.f, 0.f};
#pragma unroll
    for (int kt = 0; kt < 4; ++kt)
      acc = __builtin_amdgcn_mfma_f32_16x16x32_bf16(ah[kt], bh[kt], acc, 0, 0, 0);

    // fused epilogue for these 16 cols (identity-simplified form)
    const int col = col0 + fj * 16 + ln;
    const float sjv = sqj[fj];
    const int   ljv = labj[fj];
    float sums[4];
#pragma unroll
    for (int r = 0; r < 4; ++r) sums[r] = si[r] + sjv;
    float cd = 0.f, cp = 0.f, cn = 0.f;
#pragma unroll
    for (int r = 0; r < 4; ++r) {
      const int row = row0 + lg * 4 + r;
      const float g   = acc[r];
      const float tt  = fmaf(-2.f * C_CONST, g, 1.f);   // 1 - 2Cg
      const float den = fmaf(c2si[r], sjv, tt);         // 1 - 2Cg + C^2 si sj  (>=0)
      const float dd  = fmaf(-2.f, g, sums[r]);         // si + sj - 2g = |xi-xj|^2
      const float ns  = fmaxf(dd * den, 0.f);           // num_sq = dd*den (identity)
      const float rr  = __builtin_amdgcn_sqrtf(C_CONST * ns);
      const float dA  = fabsf(den);
      float ratio = (dA - rr) * __builtin_amdgcn_rcpf(dA + rr);
      ratio = fmaxf(ratio, RATIO_MIN);
      const float P = __builtin_amdgcn_logf(ratio);     // log2(ratio)
      const float t2 = ratio * ratio;                   // e = ratio^20
      const float t4 = t2 * t2;
      const float t5 = t4 * ratio;
      const float t10 = t5 * t5;
      const float e = t10 * t10;
      const bool mask = row < col;                      // strict upper: once/pair
      const bool same = mask && (ljv == li[r]);
      const float ev = mask ? e : 0.f;
      const float pv = same ? LOGIT_SCALE * P : 0.f;
      const float nv = same ? 1.f : 0.f;
      dacc[r] += ev; pacc[r] += pv; nacc[r] += nv;
      cd += ev; cp += pv; cn += nv;
    }
    // col-side: reduce over the 4 lg groups; per-wave LDS slice
    cd += __shfl_xor(cd, 16); cd += __shfl_xor(cd, 32);
    cp += __shfl_xor(cp, 16); cp += __shfl_xor(cp, 32);
    cn += __shfl_xor(cn, 16); cn += __shfl_xor(cn, 32);
    if (l < 16) {
      colAcc[w][0][fj * 16 + ln] = cd;
      colAcc[w][1][fj * 16 + ln] = cp;
      colAcc[w][2][fj * 16 + ln] = cn;
    }
  }

  // row-side: reduce over the 16 ln lanes -> per-wave LDS slice
#pragma unroll
  for (int r = 0; r < 4; ++r) {
    float d = dacc[r], p = pacc[r], n = nacc[r];
#pragma unroll
    for (int off = 1; off < 16; off <<= 1) {
      d += __shfl_xor(d, off);
      p += __shfl_xor(p, off);
      n += __shfl_xor(n, off);
    }
    if (ln == 0) {
      rowAcc[w][0][lg * 4 + r] = d;
      rowAcc[w][1][lg * 4 + r] = p;
      rowAcc[w][2][lg * 4 + r] = n;
    }
  }

  __syncthreads();

  // unique-writer coalesced partial stores (no atomics, no init needed)
  if (tid < 64) {
    const float rv0 = rowAcc[tid >> 4][0][tid & 15];
    const float rv1 = rowAcc[tid >> 4][1][tid & 15];
    const float rv2 = rowAcc[tid >> 4][2][tid & 15];
    const float cv0 = colAcc[0][0][tid] + colAcc[1][0][tid] + colAcc[2][0][tid] + colAcc[3][0][tid];
    const float cv1 = colAcc[0][1][tid] + colAcc[1][1][tid] + colAcc[2][1][tid] + colAcc[3][1][tid];
    const float cv2 = colAcc[0][2][tid] + colAcc[1][2][tid] + colAcc[2][2][tid] + colAcc[3][2][tid];
    if (bi == bj) {
      const size_t idx = (size_t)bi * B + bi * 64 + tid;
      dpart[idx] = rv0 + cv0;
      ppart[idx] = rv1 + cv1;
      npart[idx] = rv2 + cv2;
    } else {
      const size_t ridx = (size_t)bj * B + bi * 64 + tid;   // row-side
      dpart[ridx] = rv0; ppart[ridx] = rv1; npart[ridx] = rv2;
      const size_t cidx = (size_t)bi * B + bj * 64 + tid;   // col-side
      dpart[cidx] = cv0; ppart[cidx] = cv1; npart[cidx] = cv2;
    }
  }
}

// single finalize kernel: 16 blocks; per-block partial, then the LAST block
// (done-counter, 16 threadfences total -- negligible) reduces the 16 partials.
__global__ __launch_bounds__(256) void finalize_kernel(
    const float* __restrict__ dpart, const float* __restrict__ ppart,
    const float* __restrict__ npart, float* __restrict__ lossP,
    float* __restrict__ validP, unsigned int* __restrict__ cnt,
    float* __restrict__ out, int B) {
  const int tid = threadIdx.x;
  const int i = blockIdx.x * 256 + tid;
  float d = 0.f, p = 0.f, n = 0.f;
#pragma unroll 8
  for (int s = 0; s < NSPLIT; ++s) {
    d += dpart[(size_t)s * B + i];     // coalesced across threads
    p += ppart[(size_t)s * B + i];
    n += npart[(size_t)s * B + i];
  }
  float s_loss = 0.f, s_valid = 0.f;
  if (n > 0.f) {
    float ln_d = __builtin_amdgcn_logf(d) * LN2;
    float rl = -(p - n * ln_d) / n * TEMP;
    if (!(rl != rl)) s_loss = rl;      // NaN -> 0 like reference
    s_valid = 1.f;
  }
#pragma unroll
  for (int off = 1; off < 64; off <<= 1) {
    s_loss += __shfl_xor(s_loss, off);
    s_valid += __shfl_xor(s_valid, off);
  }
  __shared__ float red[8];
  const int wid = tid >> 6;
  if ((tid & 63) == 0) { red[wid] = s_loss; red[wid + 4] = s_valid; }
  __syncthreads();
  if (tid == 0) {
    lossP[blockIdx.x]  = red[0] + red[1] + red[2] + red[3];
    validP[blockIdx.x] = red[4] + red[5] + red[6] + red[7];
  }

  // last-block final reduce (16 threadfences total -- negligible)
  __threadfence();
  __shared__ unsigned int lastFlag;
  if (tid == 0)
    lastFlag = (atomicAdd(cnt, 1u) == (unsigned)(FBLK - 1)) ? 1u : 0u;
  __syncthreads();
  if (lastFlag != 0u && tid < 64) {
    float L = 0.f, V = 0.f;
    if (tid < FBLK) {
      L = __hip_atomic_load(&lossP[tid],  __ATOMIC_RELAXED, __HIP_MEMORY_SCOPE_AGENT);
      V = __hip_atomic_load(&validP[tid], __ATOMIC_RELAXED, __HIP_MEMORY_SCOPE_AGENT);
    }
#pragma unroll
    for (int off = 1; off < 64; off <<= 1) {
      L += __shfl_xor(L, off);
      V += __shfl_xor(V, off);
    }
    if (tid == 0) out[0] = L / fmaxf(V, 1.f);
  }
}

extern "C" void kernel_launch(void* const* d_in, const int* in_sizes, int n_in,
                              void* d_out, int out_size, void* d_ws, size_t ws_size,
                              hipStream_t stream) {
  const float* F = (const float*)d_in[0];
  const int* labels = (const int*)d_in[1];
  const int B = in_sizes[1];           // 4096

  float* sq    = (float*)d_ws;
  float* dpart = sq + B;
  float* ppart = dpart + (size_t)NSPLIT * B;
  float* npart = ppart + (size_t)NSPLIT * B;
  float* lossP = npart + (size_t)NSPLIT * B;
  float* validP = lossP + FBLK;
  unsigned int* cnt = (unsigned int*)(validP + FBLK);
  __bf16* Fh = (__bf16*)(cnt + 64);    // 256B-aligned pad

  const int nt = B / 64;                 // 64
  const int nblocks = nt * (nt + 1) / 2; // 2080

  prep_kernel<<<dim3(B / 8), dim3(256), 0, stream>>>(F, Fh, sq, cnt);
  gram_kernel<<<dim3(nblocks), dim3(256), 0, stream>>>(
      Fh, sq, labels, dpart, ppart, npart, B, nt);
  finalize_kernel<<<dim3(FBLK), dim3(256), 0, stream>>>(
      dpart, ppart, npart, lossP, validP, cnt, (float*)d_out, B);
}

// Round 22
// 34.036 us; speedup vs baseline: 1.1745x; 1.0014x over previous
//
#include <hip/hip_runtime.h>
#include <cstddef>

// Hyperbolic supervised contrastive loss: fully-fused MFMA bf16 Gram, symmetric.
// G ~= bf16(F) bf16(F)^T (validated r12-r21, absmax 0.0 vs threshold 9.4e-2).
// logits_max cancels (softmax shift invariance).
// r22: prep fused into gram -- B-tile staged from fp32 F with in-register bf16
// convert (identical cast to old prep), exact fp32 row/col norms computed
// in-block (16-lane group reduce for B rows during staging; lg-reduce for A
// rows) -> sqB/sqRow LDS. Gram block 0 zeroes the done-counter (stream order
// guarantees it precedes finalize, same as prep did). 2 kernels total.
// EPILOGUE IDENTITY (r19-proven): num_sq = (si + sj - 2g) * den,
//   den = 1 - 2Cg + C^2*si*sj >= 0.
// launch_bounds(256,4) = 128-VGPR cap: spill-free (r16's (256,8)=64-cap
// caused 143 MB scratch traffic -- the dominant failure mode found).
// NO GLOBAL ATOMICS: wedge gives every (split,row) partial a unique writer:
//   entry (s, r), br=r/64:  br<s -> block (br,s) row-side
//                           br>s -> block (s,br) col-side
//                           br==s -> diagonal block stores row+col sum
// 64x64 tiles, triangular wedge bi<=bj (nt=64, 2080 blocks), LDS ~21 KB.
// B-tile 16B-chunk XOR swizzle (c ^= row&7), linear dest + pre-swizzled src.
// Finalize: ONE kernel (16 blocks + done-counter; last block reduces).
// exp(logit) = ratio^20 via 5 mults; logit = 20*ln2*log2(ratio).

typedef __bf16 bf16x8 __attribute__((ext_vector_type(8)));
typedef float  f32x4  __attribute__((ext_vector_type(4)));

#define C_CONST 0.01f
#define RATIO_MIN 5.000025e-06f           // ratio at clamp 1-1e-5
#define LOGIT_SCALE 13.86294361119890619f // 20*ln(2)
#define TEMP 0.5f
#define LN2 0.69314718055994530942f
constexpr int DD = 128;
constexpr int NSPLIT = 64;                // = nt
constexpr int FBLK = 16;

// 64x64 tile; 4 waves, wave w owns rows row0..row0+15 (1 row-frag x 4 col-frags).
// C/D layout (verified m89): value r of frag fj at
// row = row0 + lg*4 + r, col = col0 + fj*16 + ln.
__global__ __launch_bounds__(256, 4) void gram_kernel(
    const float* __restrict__ F, const int* __restrict__ labels,
    float* __restrict__ dpart, float* __restrict__ ppart, float* __restrict__ npart,
    unsigned int* __restrict__ cnt, int B, int nt) {
  __shared__ __bf16 Bs[64 * 128];           // 16 KB B-tile, chunk-XOR swizzle
  __shared__ float colAcc[4][3][64];        // per-wave col-side slices (3 KB)
  __shared__ float rowAcc[4][3][16];        // per-wave row-side slices (768 B)
  __shared__ float sqB[64];                 // B-tile col norms (256 B)
  __shared__ float sqRow[4][16];            // per-wave A-row norms (256 B)
  char* BsB = reinterpret_cast<char*>(Bs);

  const int tid = threadIdx.x;
  const int l  = tid & 63;
  const int w  = tid >> 6;
  const int lg = l >> 4, ln = l & 15;
  const int lx = ln & 7;

  if (blockIdx.x == 0 && tid == 0) *cnt = 0u;   // finalize counter (stream-ordered)

  // triangular decode: block t -> (bi, bj), bi <= bj. S(bi) = bi*nt - bi(bi-1)/2
  const int t = blockIdx.x;
  int bi = (int)((2 * nt + 1 - sqrtf((float)((2 * nt + 1) * (2 * nt + 1) - 8 * t))) * 0.5f);
  while ((bi + 1) * nt - ((bi + 1) * bi) / 2 <= t) ++bi;
  while (bi * nt - (bi * (bi - 1)) / 2 > t) --bi;
  const int bj = bi + (t - (bi * nt - (bi * (bi - 1)) / 2));

  const int row0 = bi * 64 + w * 16;
  const int col0 = bj * 64;

  // --- stage B tile from fp32 F: convert to bf16 in-reg, linear LDS dest with
  // pre-swizzled source chunk; accumulate exact fp32 col norms while staging.
  // LDS chunk k (16B) of row r holds global chunk ((k&15) ^ (r&7)) of row r.
#pragma unroll
  for (int j = 0; j < 4; ++j) {
    const int k = tid + j * 256;            // chunk id 0..1023
    const int row = k >> 4;
    const int cc = (k & 15) ^ (row & 7);
    const float* src = F + (size_t)(col0 + row) * DD + cc * 8;
    const float4 v0 = *reinterpret_cast<const float4*>(src);
    const float4 v1 = *reinterpret_cast<const float4*>(src + 4);
    bf16x8 hv;
    hv[0] = (__bf16)v0.x; hv[1] = (__bf16)v0.y; hv[2] = (__bf16)v0.z; hv[3] = (__bf16)v0.w;
    hv[4] = (__bf16)v1.x; hv[5] = (__bf16)v1.y; hv[6] = (__bf16)v1.z; hv[7] = (__bf16)v1.w;
    *reinterpret_cast<bf16x8*>(BsB + (size_t)k * 16) = hv;
    float s = v0.x * v0.x + v0.y * v0.y + v0.z * v0.z + v0.w * v0.w
            + v1.x * v1.x + v1.y * v1.y + v1.z * v1.z + v1.w * v1.w;
    s += __shfl_xor(s, 1); s += __shfl_xor(s, 2);
    s += __shfl_xor(s, 4); s += __shfl_xor(s, 8);   // 16 chunks of this row
    if ((tid & 15) == 0) sqB[row] = s;
  }

  // --- A fragments from fp32 F: convert in-reg; exact fp32 row norms via lg-reduce
  const float* Afp = F + (size_t)(row0 + ln) * DD + lg * 8;
  bf16x8 ah[4];
  float an = 0.f;
#pragma unroll
  for (int kt = 0; kt < 4; ++kt) {
    const float4 u0 = *reinterpret_cast<const float4*>(Afp + kt * 32);
    const float4 u1 = *reinterpret_cast<const float4*>(Afp + kt * 32 + 4);
    bf16x8 hv;
    hv[0] = (__bf16)u0.x; hv[1] = (__bf16)u0.y; hv[2] = (__bf16)u0.z; hv[3] = (__bf16)u0.w;
    hv[4] = (__bf16)u1.x; hv[5] = (__bf16)u1.y; hv[6] = (__bf16)u1.z; hv[7] = (__bf16)u1.w;
    ah[kt] = hv;
    an += u0.x * u0.x + u0.y * u0.y + u0.z * u0.z + u0.w * u0.w
        + u1.x * u1.x + u1.y * u1.y + u1.z * u1.z + u1.w * u1.w;
  }
  an += __shfl_xor(an, 16);
  an += __shfl_xor(an, 32);                 // 4 lg slices of row row0+ln
  if (l < 16) sqRow[w][ln] = an;

  // labels hoisted (independent of LDS)
  int li[4];
#pragma unroll
  for (int r = 0; r < 4; ++r) li[r] = labels[row0 + lg * 4 + r];
  int labj[4];
#pragma unroll
  for (int fj = 0; fj < 4; ++fj) labj[fj] = labels[col0 + fj * 16 + ln];

  __syncthreads();

  float si[4], c2si[4];
#pragma unroll
  for (int r = 0; r < 4; ++r) {
    si[r] = sqRow[w][lg * 4 + r];
    c2si[r] = (C_CONST * C_CONST) * si[r];
  }
  float sqj[4];
#pragma unroll
  for (int fj = 0; fj < 4; ++fj) sqj[fj] = sqB[fj * 16 + ln];

  float dacc[4] = {}, pacc[4] = {}, nacc[4] = {};

#pragma unroll
  for (int fj = 0; fj < 4; ++fj) {
    // 4 ds_read_b128 (swizzled)
    const int rbase = (fj * 16 + ln) * 256;
    bf16x8 bh[4];
#pragma unroll
    for (int kt = 0; kt < 4; ++kt)
      bh[kt] = *reinterpret_cast<const bf16x8*>(BsB + rbase + ((((kt * 4 + lg) ^ lx)) << 4));

    f32x4 acc = (f32x4){0.f, 0.f, 0.f, 0.f};
#pragma unroll
    for (int kt = 0; kt < 4; ++kt)
      acc = __builtin_amdgcn_mfma_f32_16x16x32_bf16(ah[kt], bh[kt], acc, 0, 0, 0);

    // fused epilogue for these 16 cols (identity-simplified form)
    const int col = col0 + fj * 16 + ln;
    const float sjv = sqj[fj];
    const int   ljv = labj[fj];
    float sums[4];
#pragma unroll
    for (int r = 0; r < 4; ++r) sums[r] = si[r] + sjv;
    float cd = 0.f, cp = 0.f, cn = 0.f;
#pragma unroll
    for (int r = 0; r < 4; ++r) {
      const int row = row0 + lg * 4 + r;
      const float g   = acc[r];
      const float tt  = fmaf(-2.f * C_CONST, g, 1.f);   // 1 - 2Cg
      const float den = fmaf(c2si[r], sjv, tt);         // 1 - 2Cg + C^2 si sj  (>=0)
      const float dd  = fmaf(-2.f, g, sums[r]);         // si + sj - 2g = |xi-xj|^2
      const float ns  = fmaxf(dd * den, 0.f);           // num_sq = dd*den (identity)
      const float rr  = __builtin_amdgcn_sqrtf(C_CONST * ns);
      const float dA  = fabsf(den);
      float ratio = (dA - rr) * __builtin_amdgcn_rcpf(dA + rr);
      ratio = fmaxf(ratio, RATIO_MIN);
      const float P = __builtin_amdgcn_logf(ratio);     // log2(ratio)
      const float t2 = ratio * ratio;                   // e = ratio^20
      const float t4 = t2 * t2;
      const float t5 = t4 * ratio;
      const float t10 = t5 * t5;
      const float e = t10 * t10;
      const bool mask = row < col;                      // strict upper: once/pair
      const bool same = mask && (ljv == li[r]);
      const float ev = mask ? e : 0.f;
      const float pv = same ? LOGIT_SCALE * P : 0.f;
      const float nv = same ? 1.f : 0.f;
      dacc[r] += ev; pacc[r] += pv; nacc[r] += nv;
      cd += ev; cp += pv; cn += nv;
    }
    // col-side: reduce over the 4 lg groups; per-wave LDS slice
    cd += __shfl_xor(cd, 16); cd += __shfl_xor(cd, 32);
    cp += __shfl_xor(cp, 16); cp += __shfl_xor(cp, 32);
    cn += __shfl_xor(cn, 16); cn += __shfl_xor(cn, 32);
    if (l < 16) {
      colAcc[w][0][fj * 16 + ln] = cd;
      colAcc[w][1][fj * 16 + ln] = cp;
      colAcc[w][2][fj * 16 + ln] = cn;
    }
  }

  // row-side: reduce over the 16 ln lanes -> per-wave LDS slice
#pragma unroll
  for (int r = 0; r < 4; ++r) {
    float d = dacc[r], p = pacc[r], n = nacc[r];
#pragma unroll
    for (int off = 1; off < 16; off <<= 1) {
      d += __shfl_xor(d, off);
      p += __shfl_xor(p, off);
      n += __shfl_xor(n, off);
    }
    if (ln == 0) {
      rowAcc[w][0][lg * 4 + r] = d;
      rowAcc[w][1][lg * 4 + r] = p;
      rowAcc[w][2][lg * 4 + r] = n;
    }
  }

  __syncthreads();

  // unique-writer coalesced partial stores (no atomics, no init needed)
  if (tid < 64) {
    const float rv0 = rowAcc[tid >> 4][0][tid & 15];
    const float rv1 = rowAcc[tid >> 4][1][tid & 15];
    const float rv2 = rowAcc[tid >> 4][2][tid & 15];
    const float cv0 = colAcc[0][0][tid] + colAcc[1][0][tid] + colAcc[2][0][tid] + colAcc[3][0][tid];
    const float cv1 = colAcc[0][1][tid] + colAcc[1][1][tid] + colAcc[2][1][tid] + colAcc[3][1][tid];
    const float cv2 = colAcc[0][2][tid] + colAcc[1][2][tid] + colAcc[2][2][tid] + colAcc[3][2][tid];
    if (bi == bj) {
      const size_t idx = (size_t)bi * B + bi * 64 + tid;
      dpart[idx] = rv0 + cv0;
      ppart[idx] = rv1 + cv1;
      npart[idx] = rv2 + cv2;
    } else {
      const size_t ridx = (size_t)bj * B + bi * 64 + tid;   // row-side
      dpart[ridx] = rv0; ppart[ridx] = rv1; npart[ridx] = rv2;
      const size_t cidx = (size_t)bi * B + bj * 64 + tid;   // col-side
      dpart[cidx] = cv0; ppart[cidx] = cv1; npart[cidx] = cv2;
    }
  }
}

// single finalize kernel: 16 blocks; per-block partial, then the LAST block
// (done-counter, 16 threadfences total -- negligible) reduces the 16 partials.
__global__ __launch_bounds__(256) void finalize_kernel(
    const float* __restrict__ dpart, const float* __restrict__ ppart,
    const float* __restrict__ npart, float* __restrict__ lossP,
    float* __restrict__ validP, unsigned int* __restrict__ cnt,
    float* __restrict__ out, int B) {
  const int tid = threadIdx.x;
  const int i = blockIdx.x * 256 + tid;
  float d = 0.f, p = 0.f, n = 0.f;
#pragma unroll 8
  for (int s = 0; s < NSPLIT; ++s) {
    d += dpart[(size_t)s * B + i];     // coalesced across threads
    p += ppart[(size_t)s * B + i];
    n += npart[(size_t)s * B + i];
  }
  float s_loss = 0.f, s_valid = 0.f;
  if (n > 0.f) {
    float ln_d = __builtin_amdgcn_logf(d) * LN2;
    float rl = -(p - n * ln_d) / n * TEMP;
    if (!(rl != rl)) s_loss = rl;      // NaN -> 0 like reference
    s_valid = 1.f;
  }
#pragma unroll
  for (int off = 1; off < 64; off <<= 1) {
    s_loss += __shfl_xor(s_loss, off);
    s_valid += __shfl_xor(s_valid, off);
  }
  __shared__ float red[8];
  const int wid = tid >> 6;
  if ((tid & 63) == 0) { red[wid] = s_loss; red[wid + 4] = s_valid; }
  __syncthreads();
  if (tid == 0) {
    lossP[blockIdx.x]  = red[0] + red[1] + red[2] + red[3];
    validP[blockIdx.x] = red[4] + red[5] + red[6] + red[7];
  }

  // last-block final reduce (16 threadfences total -- negligible)
  __threadfence();
  __shared__ unsigned int lastFlag;
  if (tid == 0)
    lastFlag = (atomicAdd(cnt, 1u) == (unsigned)(FBLK - 1)) ? 1u : 0u;
  __syncthreads();
  if (lastFlag != 0u && tid < 64) {
    float L = 0.f, V = 0.f;
    if (tid < FBLK) {
      L = __hip_atomic_load(&lossP[tid],  __ATOMIC_RELAXED, __HIP_MEMORY_SCOPE_AGENT);
      V = __hip_atomic_load(&validP[tid], __ATOMIC_RELAXED, __HIP_MEMORY_SCOPE_AGENT);
    }
#pragma unroll
    for (int off = 1; off < 64; off <<= 1) {
      L += __shfl_xor(L, off);
      V += __shfl_xor(V, off);
    }
    if (tid == 0) out[0] = L / fmaxf(V, 1.f);
  }
}

extern "C" void kernel_launch(void* const* d_in, const int* in_sizes, int n_in,
                              void* d_out, int out_size, void* d_ws, size_t ws_size,
                              hipStream_t stream) {
  const float* F = (const float*)d_in[0];
  const int* labels = (const int*)d_in[1];
  const int B = in_sizes[1];           // 4096

  float* dpart = (float*)d_ws;
  float* ppart = dpart + (size_t)NSPLIT * B;
  float* npart = ppart + (size_t)NSPLIT * B;
  float* lossP = npart + (size_t)NSPLIT * B;
  float* validP = lossP + FBLK;
  unsigned int* cnt = (unsigned int*)(validP + FBLK);

  const int nt = B / 64;                 // 64
  const int nblocks = nt * (nt + 1) / 2; // 2080

  gram_kernel<<<dim3(nblocks), dim3(256), 0, stream>>>(
      F, labels, dpart, ppart, npart, cnt, B, nt);
  finalize_kernel<<<dim3(FBLK), dim3(256), 0, stream>>>(
      dpart, ppart, npart, lossP, validP, cnt, (float*)d_out, B);
}